// Round 8
// baseline (433.448 us; speedup 1.0000x reference)
//
#include <hip/hip_runtime.h>
#include <hip/hip_bf16.h>
#include <cstddef>

// Fused 3-layer LSTM, wavefront-pipelined, swapped-operand MFMA, 12 waves.
// Block = 16 batches, 768 threads, 1 block/CU, 3 waves/SIMD.
// Roles: w0-2 L0 tiles {0-4},{5-8},{9-12}(+x-stage on w2); w3-6 L1 NT=3;
// w7-10 L2 NT=3; w11 fused dual-orphan (L1 tile12 + L2 tile12, interleaved).
// Skew: iter it -> L0@t=it, L1@t=it-1, L2@t=it-2. ONE s_barrier/iter.
// Per-term accumulators (3 chains of depth KS) break the 12-deep MFMA
// dependence chain; s_setprio(1) wraps the MFMA cluster.
// Act LDS fragment-major: addr(k,b) = (k>>3)*128 + b*8 + (k&7) shorts.
// Bias rides act==1.0 column: L0 k=58, L1/L2 k=100.

#define T_STEPS 256
#define BTOT    4096
#define NTHR    768

typedef __attribute__((ext_vector_type(8))) short short8;
typedef __attribute__((ext_vector_type(4))) float f32x4;

#define BAR() do { \
    asm volatile("s_waitcnt lgkmcnt(0)" ::: "memory"); \
    __builtin_amdgcn_sched_barrier(0); \
    __builtin_amdgcn_s_barrier(); \
    __builtin_amdgcn_sched_barrier(0); \
} while (0)

__device__ __forceinline__ float fast_sigmoid(float x) {
    float e = __builtin_amdgcn_exp2f(-1.4426950408889634f * x);
    return __builtin_amdgcn_rcpf(1.0f + e);
}
__device__ __forceinline__ float fast_tanh(float x) {
    float e = __builtin_amdgcn_exp2f(2.8853900817779268f * x);
    return 1.0f - 2.0f * __builtin_amdgcn_rcpf(1.0f + e);
}
__device__ __forceinline__ unsigned short f2bf(float x) {
    union { __hip_bfloat16 b; unsigned short s; } u;
    u.b = __float2bfloat16(x);
    return u.s;
}
__device__ __forceinline__ float bf2f(unsigned short s) {
    union { unsigned u; float f; } v; v.u = (unsigned)s << 16; return v.f;
}
// Trunc split: (hi<<16)|lo bits of v ~ hi + lo with |err| <= 2^-14 |v|.
__device__ __forceinline__ unsigned split2(float v) {
    union { float f; unsigned u; } x; x.f = v;
    union { unsigned u; float f; } h; h.u = x.u & 0xFFFF0000u;
    union { float f; unsigned u; } y; y.f = v - h.f;
    return (x.u & 0xFFFF0000u) | (y.u >> 16);
}
// gates (i,f,g,o) -> new h; updates cst.
__device__ __forceinline__ float cell_upd(f32x4 g, float& cst) {
    float ig = fast_sigmoid(g[0]);
    float fg = fast_sigmoid(g[1]);
    float gg = fast_tanh(g[2]);
    float og = fast_sigmoid(g[3]);
    float c  = fmaf(fg, cst, ig * gg);
    cst = c;
    return og * fast_tanh(c);
}

// Weights -> (hi,lo) frags. K-packed [w_ih(XK) | w_hh(50) | bias@BIASK].
// Row N' = (T0+q)*16 + (lane&15), k = ks*32 + (lane>>4)*8 + e.
template<int NT, int KS, int XK, int BIASK>
__device__ __forceinline__ void load_wb(int T0, int lane,
    const float* __restrict__ w_ih, const float* __restrict__ w_hh,
    const float* __restrict__ b_ih, const float* __restrict__ b_hh,
    short8 (&Wh)[NT][KS], short8 (&Wl)[NT][KS])
{
    const int m = lane & 15, kg = lane >> 4;
    #pragma unroll
    for (int q = 0; q < NT; ++q) {
        int gp = (T0 + q) * 16 + m;
        int gr = (gp < 200) ? ((gp & 3) * 50 + (gp >> 2)) : -1;
        #pragma unroll
        for (int ks = 0; ks < KS; ++ks)
            #pragma unroll
            for (int e = 0; e < 8; ++e) {
                int k = ks * 32 + kg * 8 + e;
                float v = 0.0f;
                if (gr >= 0) {
                    if (k < XK) v = w_ih[gr * XK + k];
                    else if (k < XK + 50) v = w_hh[gr * 50 + (k - XK)];
                    else if (k == BIASK) v = b_ih[gr] + b_hh[gr];
                }
                unsigned short hb = f2bf(v);
                Wh[q][ks][e] = (short)hb;
                Wl[q][ks][e] = (short)f2bf(v - bf2f(hb));
            }
    }
}

// One layer-step. Per-term accumulators (NACC chains), setprio'd MFMA cluster,
// in-register cell update, trunc-split h writes.
template<int T0, int NT, int KS, int NACC, int HK, bool WRB, bool LASTL>
__device__ __forceinline__ void step_body(
    int t, int lane,
    const short* Arh, const short* Arl,
    short* Awh, short* Awl,
    short* Axh, short* Axl,
    float* hfp,
    const short8 (&Wh)[NT][KS], const short8 (&Wl)[NT][KS],
    float (&cst)[NT])
{
    const int b = lane & 15, kg = lane >> 4;

    f32x4 acc[NT][NACC];
    #pragma unroll
    for (int q = 0; q < NT; ++q)
        #pragma unroll
        for (int j = 0; j < NACC; ++j)
            acc[q][j] = (f32x4){0.0f, 0.0f, 0.0f, 0.0f};

    __builtin_amdgcn_s_setprio(1);
    #pragma unroll
    for (int ks = 0; ks < KS; ++ks) {
        int ga = (ks * 4 + kg) * 128 + b * 8;
        short8 Ah = *(const short8*)&Arh[ga];
        short8 Al = *(const short8*)&Arl[ga];
        #pragma unroll
        for (int q = 0; q < NT; ++q)
            acc[q][(ks * 3 + 0) % NACC] =
                __builtin_amdgcn_mfma_f32_16x16x32_bf16(Wh[q][ks], Ah, acc[q][(ks * 3 + 0) % NACC], 0, 0, 0);
        #pragma unroll
        for (int q = 0; q < NT; ++q)
            acc[q][(ks * 3 + 1) % NACC] =
                __builtin_amdgcn_mfma_f32_16x16x32_bf16(Wl[q][ks], Ah, acc[q][(ks * 3 + 1) % NACC], 0, 0, 0);
        #pragma unroll
        for (int q = 0; q < NT; ++q)
            acc[q][(ks * 3 + 2) % NACC] =
                __builtin_amdgcn_mfma_f32_16x16x32_bf16(Wh[q][ks], Al, acc[q][(ks * 3 + 2) % NACC], 0, 0, 0);
    }
    __builtin_amdgcn_s_setprio(0);

    #pragma unroll
    for (int q = 0; q < NT; ++q) {
        const int nb = (T0 + q) * 4;               // compile-time
        int n = nb + kg;
        if (nb < 48 || kg < 2) {                   // tile 12 -> guard kg<2
            f32x4 g = acc[q][0];
            #pragma unroll
            for (int j = 1; j < NACC; ++j) g += acc[q][j];
            float h = cell_upd(g, cst[q]);
            unsigned p = split2(h);
            int k  = HK + n;
            int ad = (k >> 3) * 128 + b * 8 + (k & 7);
            Awh[ad] = (short)(p >> 16);
            Awl[ad] = (short)p;
            if (WRB) {
                int ad2 = (n >> 3) * 128 + b * 8 + (n & 7);
                Axh[ad2] = (short)(p >> 16);
                Axl[ad2] = (short)p;
            }
            if (LASTL && t == T_STEPS - 1) hfp[b * 56 + n] = h;
        }
    }
}

template<int T0, int NT, bool XST>
__device__ void role_l0(int lane, int b0, const float* __restrict__ xf,
    const float* w_ih, const float* w_hh, const float* b_ih, const float* b_hh,
    short (*A0h)[1024], short (*A0l)[1024],
    short (*A1h)[2048], short (*A1l)[2048])
{
    short8 Wh[NT][2], Wl[NT][2];
    load_wb<NT, 2, 8, 58>(T0, lane, w_ih, w_hh, b_ih, b_hh, Wh, Wl);
    float cst[NT];
    #pragma unroll
    for (int q = 0; q < NT; ++q) cst[q] = 0.0f;
    const int bb = lane & 15, kg = lane >> 4;

    for (int it = 0; it < T_STEPS + 2; ++it) {
        const bool stg = XST && (kg == 0) && (it + 1 < T_STEPS);
        float xs[8];
        if (stg) {
            const float* xr = &xf[((size_t)(b0 + bb) * T_STEPS + (it + 1)) * 8];
            *(float4*)&xs[0] = *(const float4*)xr;
            *(float4*)&xs[4] = *(const float4*)(xr + 4);
        }
        if (it < T_STEPS) {
            int cur = it & 1, nxt = cur ^ 1;
            step_body<T0, NT, 2, 2, 8, true, false>(it, lane,
                A0h[cur], A0l[cur], A0h[nxt], A0l[nxt],
                A1h[cur], A1l[cur], nullptr, Wh, Wl, cst);
        }
        if (stg) {
            int nb = (it + 1) & 1;
            short8 hi, lo;
            #pragma unroll
            for (int e = 0; e < 8; ++e) {
                unsigned p = split2(xs[e]);
                hi[e] = (short)(p >> 16);
                lo[e] = (short)p;
            }
            *(short8*)&A0h[nb][bb * 8] = hi;
            *(short8*)&A0l[nb][bb * 8] = lo;
        }
        BAR();
    }
}

// Mid-layer wave, NT=3. LASTL: L2 (skew 2, hf at t=255); else L1 (-> A2).
template<int T0, bool LASTL>
__device__ void role_mid(int lane,
    const float* w_ih, const float* w_hh, const float* b_ih, const float* b_hh,
    short (*Arh)[2048], short (*Arl)[2048],
    short (*Axh)[2048], short (*Axl)[2048],
    float* hfp)
{
    constexpr int SKEW = LASTL ? 2 : 1;
    short8 Wh[3][4], Wl[3][4];
    load_wb<3, 4, 50, 100>(T0, lane, w_ih, w_hh, b_ih, b_hh, Wh, Wl);
    float cst[3] = {0.0f, 0.0f, 0.0f};

    for (int it = 0; it < T_STEPS + 2; ++it) {
        int t = it - SKEW;
        if (t >= 0 && t < T_STEPS) {
            step_body<T0, 3, 4, 3, 50, !LASTL, LASTL>(t, lane,
                Arh[t & 1], Arl[t & 1], Arh[(t + 1) & 1], Arl[(t + 1) & 1],
                LASTL ? (short*)nullptr : Axh[t & 1],
                LASTL ? (short*)nullptr : Axl[t & 1],
                hfp, Wh, Wl, cst);
        }
        BAR();
    }
}

// Fused dual-orphan: L1 tile12 (t1=it-1) and L2 tile12 (t2=it-2), MFMA and
// update sections interleaved so the two serial chains overlap.
__device__ void role_orphan(int lane,
    const float* w_ih1, const float* w_hh1, const float* b_ih1, const float* b_hh1,
    const float* w_ih2, const float* w_hh2, const float* b_ih2, const float* b_hh2,
    short (*A1h)[2048], short (*A1l)[2048],
    short (*A2h)[2048], short (*A2l)[2048],
    float* hfp)
{
    short8 W1h[1][4], W1l[1][4], W2h[1][4], W2l[1][4];
    load_wb<1, 4, 50, 100>(12, lane, w_ih1, w_hh1, b_ih1, b_hh1, W1h, W1l);
    load_wb<1, 4, 50, 100>(12, lane, w_ih2, w_hh2, b_ih2, b_hh2, W2h, W2l);
    float c1 = 0.0f, c2 = 0.0f;
    const int b = lane & 15, kg = lane >> 4;

    for (int it = 0; it < T_STEPS + 2; ++it) {
        int t1 = it - 1, t2 = it - 2;
        bool d1 = (unsigned)t1 < T_STEPS, d2 = (unsigned)t2 < T_STEPS;

        f32x4 a1[3], a2[3];
        #pragma unroll
        for (int j = 0; j < 3; ++j) {
            a1[j] = (f32x4){0.0f, 0.0f, 0.0f, 0.0f};
            a2[j] = (f32x4){0.0f, 0.0f, 0.0f, 0.0f};
        }

        __builtin_amdgcn_s_setprio(1);
        #pragma unroll
        for (int ks = 0; ks < 4; ++ks) {
            int ga = (ks * 4 + kg) * 128 + b * 8;
            if (d1) {
                short8 Ah = *(const short8*)&A1h[t1 & 1][ga];
                short8 Al = *(const short8*)&A1l[t1 & 1][ga];
                a1[0] = __builtin_amdgcn_mfma_f32_16x16x32_bf16(W1h[0][ks], Ah, a1[0], 0, 0, 0);
                a1[1] = __builtin_amdgcn_mfma_f32_16x16x32_bf16(W1l[0][ks], Ah, a1[1], 0, 0, 0);
                a1[2] = __builtin_amdgcn_mfma_f32_16x16x32_bf16(W1h[0][ks], Al, a1[2], 0, 0, 0);
            }
            if (d2) {
                short8 Ah = *(const short8*)&A2h[t2 & 1][ga];
                short8 Al = *(const short8*)&A2l[t2 & 1][ga];
                a2[0] = __builtin_amdgcn_mfma_f32_16x16x32_bf16(W2h[0][ks], Ah, a2[0], 0, 0, 0);
                a2[1] = __builtin_amdgcn_mfma_f32_16x16x32_bf16(W2l[0][ks], Ah, a2[1], 0, 0, 0);
                a2[2] = __builtin_amdgcn_mfma_f32_16x16x32_bf16(W2h[0][ks], Al, a2[2], 0, 0, 0);
            }
        }
        __builtin_amdgcn_s_setprio(0);

        const int n = 48 + kg;                     // valid kg<2
        if (d1 && kg < 2) {
            f32x4 g = a1[0] + a1[1] + a1[2];
            float h = cell_upd(g, c1);
            unsigned p = split2(h);
            int k = 50 + n;
            int ad = (k >> 3) * 128 + b * 8 + (k & 7);
            A1h[(t1 + 1) & 1][ad] = (short)(p >> 16);
            A1l[(t1 + 1) & 1][ad] = (short)p;
            int ad2 = (n >> 3) * 128 + b * 8 + (n & 7);
            A2h[t1 & 1][ad2] = (short)(p >> 16);
            A2l[t1 & 1][ad2] = (short)p;
        }
        if (d2 && kg < 2) {
            f32x4 g = a2[0] + a2[1] + a2[2];
            float h = cell_upd(g, c2);
            unsigned p = split2(h);
            int k = 50 + n;
            int ad = (k >> 3) * 128 + b * 8 + (k & 7);
            A2h[(t2 + 1) & 1][ad] = (short)(p >> 16);
            A2l[(t2 + 1) & 1][ad] = (short)p;
            if (t2 == T_STEPS - 1) hfp[b * 56 + n] = h;
        }
        BAR();
    }
}

__global__ __launch_bounds__(NTHR, 3) void lstm_fused(
    const float* __restrict__ xf,
    const float* w_ih0, const float* w_hh0, const float* b_ih0, const float* b_hh0,
    const float* w_ih1, const float* w_hh1, const float* b_ih1, const float* b_hh1,
    const float* w_ih2, const float* w_hh2, const float* b_ih2, const float* b_hh2,
    const float* __restrict__ w_fc, const float* __restrict__ b_fc,
    float* __restrict__ out)
{
    __shared__ __align__(16) short A0h[2][1024], A0l[2][1024];   // L0 act (K=64)
    __shared__ __align__(16) short A1h[2][2048], A1l[2][2048];   // L1 act (K=128)
    __shared__ __align__(16) short A2h[2][2048], A2l[2][2048];   // L2 act (K=128)
    __shared__ __align__(16) float hf[16 * 56];

    const int tid  = threadIdx.x;
    const int lane = tid & 63;
    const int wid  = tid >> 6;
    const int b0   = blockIdx.x * 16;

    for (int i = tid; i < 2048; i += NTHR) { ((short*)A0h)[i] = 0; ((short*)A0l)[i] = 0; }
    for (int i = tid; i < 4096; i += NTHR) {
        ((short*)A1h)[i] = 0; ((short*)A1l)[i] = 0;
        ((short*)A2h)[i] = 0; ((short*)A2l)[i] = 0;
    }
    __syncthreads();

    if (tid < 32) {
        int buf = tid >> 4, b = tid & 15;
        A0h[buf][(58 >> 3) * 128 + b * 8 + (58 & 7)] = (short)0x3F80;
        A1h[buf][(100 >> 3) * 128 + b * 8 + (100 & 7)] = (short)0x3F80;
        A2h[buf][(100 >> 3) * 128 + b * 8 + (100 & 7)] = (short)0x3F80;
    }
    if (tid < 16) {
        int b = tid;
        #pragma unroll
        for (int j = 0; j < 8; ++j) {
            float v = xf[((size_t)(b0 + b) * T_STEPS + 0) * 8 + j];
            unsigned p = split2(v);
            A0h[0][b * 8 + j] = (short)(p >> 16);
            A0l[0][b * 8 + j] = (short)p;
        }
    }
    __syncthreads();

    if      (wid == 0)  role_l0<0, 5, false>(lane, b0, xf, w_ih0, w_hh0, b_ih0, b_hh0, A0h, A0l, A1h, A1l);
    else if (wid == 1)  role_l0<5, 4, false>(lane, b0, xf, w_ih0, w_hh0, b_ih0, b_hh0, A0h, A0l, A1h, A1l);
    else if (wid == 2)  role_l0<9, 4, true >(lane, b0, xf, w_ih0, w_hh0, b_ih0, b_hh0, A0h, A0l, A1h, A1l);
    else if (wid == 3)  role_mid<0, false>(lane, w_ih1, w_hh1, b_ih1, b_hh1, A1h, A1l, A2h, A2l, nullptr);
    else if (wid == 4)  role_mid<3, false>(lane, w_ih1, w_hh1, b_ih1, b_hh1, A1h, A1l, A2h, A2l, nullptr);
    else if (wid == 5)  role_mid<6, false>(lane, w_ih1, w_hh1, b_ih1, b_hh1, A1h, A1l, A2h, A2l, nullptr);
    else if (wid == 6)  role_mid<9, false>(lane, w_ih1, w_hh1, b_ih1, b_hh1, A1h, A1l, A2h, A2l, nullptr);
    else if (wid == 7)  role_mid<0, true >(lane, w_ih2, w_hh2, b_ih2, b_hh2, A2h, A2l, nullptr, nullptr, hf);
    else if (wid == 8)  role_mid<3, true >(lane, w_ih2, w_hh2, b_ih2, b_hh2, A2h, A2l, nullptr, nullptr, hf);
    else if (wid == 9)  role_mid<6, true >(lane, w_ih2, w_hh2, b_ih2, b_hh2, A2h, A2l, nullptr, nullptr, hf);
    else if (wid == 10) role_mid<9, true >(lane, w_ih2, w_hh2, b_ih2, b_hh2, A2h, A2l, nullptr, nullptr, hf);
    else                role_orphan(lane,
                            w_ih1, w_hh1, b_ih1, b_hh1,
                            w_ih2, w_hh2, b_ih2, b_hh2,
                            A1h, A1l, A2h, A2l, hf);

    __syncthreads();

    if (tid < 96) {
        int b = tid / 6, o = tid - b * 6;
        float a = b_fc[o];
        #pragma unroll
        for (int n = 0; n < 50; ++n)
            a = fmaf(w_fc[o * 50 + n], hf[b * 56 + n], a);
        out[(size_t)(b0 + b) * 6 + o] = a;
    }
}

extern "C" void kernel_launch(void* const* d_in, const int* in_sizes, int n_in,
                              void* d_out, int out_size, void* d_ws, size_t ws_size,
                              hipStream_t stream) {
    (void)in_sizes; (void)n_in; (void)d_ws; (void)ws_size; (void)out_size;

    const float* x     = (const float*)d_in[0];
    const float* w_ih0 = (const float*)d_in[1];
    const float* w_hh0 = (const float*)d_in[2];
    const float* b_ih0 = (const float*)d_in[3];
    const float* b_hh0 = (const float*)d_in[4];
    const float* w_ih1 = (const float*)d_in[5];
    const float* w_hh1 = (const float*)d_in[6];
    const float* b_ih1 = (const float*)d_in[7];
    const float* b_hh1 = (const float*)d_in[8];
    const float* w_ih2 = (const float*)d_in[9];
    const float* w_hh2 = (const float*)d_in[10];
    const float* b_ih2 = (const float*)d_in[11];
    const float* b_hh2 = (const float*)d_in[12];
    const float* w_fc  = (const float*)d_in[13];
    const float* b_fc  = (const float*)d_in[14];
    float* out = (float*)d_out;

    lstm_fused<<<dim3(BTOT / 16), dim3(NTHR), 0, stream>>>(
        x, w_ih0, w_hh0, b_ih0, b_hh0, w_ih1, w_hh1, b_ih1, b_hh1,
        w_ih2, w_hh2, b_ih2, b_hh2, w_fc, b_fc, out);
}

// Round 9
// 304.757 us; speedup vs baseline: 1.4223x; 1.4223x over previous
//
#include <hip/hip_runtime.h>
#include <hip/hip_bf16.h>
#include <cstddef>

// Fused 3-layer LSTM, wavefront-pipelined, swapped-operand MFMA, 12 waves.
// Block = 16 batches, 768 threads, 1 block/CU, 3 waves/SIMD.
// Roles: w0-2 L0 tiles {0-4},{5-8},{9-12} (w2 stages x); w3-6 L1 NT=3;
// w7-10 L2 NT=3; w11 fused dual-orphan (L1 tile12 + L2 tile12).
// Skew: iter it -> L0@t=it, L1@t=it-1, L2@t=it-2. ONE s_barrier/iter.
//
// 2-TERM bf16 split (R9): weights kept as (hi,lo); activations RNE bf16 ONLY.
// gates ~= Wh*Ah + Wl*Ah. Act LDS reads/writes, MFMA count, and acc traffic
// all halve vs the 3-term R6 kernel. Act layout fragment-major:
// addr(k,b) = (k>>3)*128 + b*8 + (k&7) shorts -> frag reads are linear 16B/lane.
// Bias rides act==1.0 column: L0 k=58, L1/L2 k=100.

#define T_STEPS 256
#define BTOT    4096
#define NTHR    768

typedef __attribute__((ext_vector_type(8))) short short8;
typedef __attribute__((ext_vector_type(4))) float f32x4;

#define BAR() do { \
    asm volatile("s_waitcnt lgkmcnt(0)" ::: "memory"); \
    __builtin_amdgcn_sched_barrier(0); \
    __builtin_amdgcn_s_barrier(); \
    __builtin_amdgcn_sched_barrier(0); \
} while (0)

__device__ __forceinline__ float fast_sigmoid(float x) {
    float e = __builtin_amdgcn_exp2f(-1.4426950408889634f * x);
    return __builtin_amdgcn_rcpf(1.0f + e);
}
__device__ __forceinline__ float fast_tanh(float x) {
    float e = __builtin_amdgcn_exp2f(2.8853900817779268f * x);
    return 1.0f - 2.0f * __builtin_amdgcn_rcpf(1.0f + e);
}
__device__ __forceinline__ unsigned short f2bf(float x) {     // RNE
    union { __hip_bfloat16 b; unsigned short s; } u;
    u.b = __float2bfloat16(x);
    return u.s;
}
__device__ __forceinline__ float bf2f(unsigned short s) {
    union { unsigned u; float f; } v; v.u = (unsigned)s << 16; return v.f;
}
// gates (i,f,g,o) -> new h; updates cst.
__device__ __forceinline__ float cell_upd(f32x4 g, float& cst) {
    float ig = fast_sigmoid(g[0]);
    float fg = fast_sigmoid(g[1]);
    float gg = fast_tanh(g[2]);
    float og = fast_sigmoid(g[3]);
    float c  = fmaf(fg, cst, ig * gg);
    cst = c;
    return og * fast_tanh(c);
}

// Weights -> (hi,lo) frags. K-packed [w_ih(XK) | w_hh(50) | bias@BIASK].
// Row N' = (T0+q)*16 + (lane&15), k = ks*32 + (lane>>4)*8 + e.
template<int NT, int KS, int XK, int BIASK>
__device__ __forceinline__ void load_wb(int T0, int lane,
    const float* __restrict__ w_ih, const float* __restrict__ w_hh,
    const float* __restrict__ b_ih, const float* __restrict__ b_hh,
    short8 (&Wh)[NT][KS], short8 (&Wl)[NT][KS])
{
    const int m = lane & 15, kg = lane >> 4;
    #pragma unroll
    for (int q = 0; q < NT; ++q) {
        int gp = (T0 + q) * 16 + m;
        int gr = (gp < 200) ? ((gp & 3) * 50 + (gp >> 2)) : -1;
        #pragma unroll
        for (int ks = 0; ks < KS; ++ks)
            #pragma unroll
            for (int e = 0; e < 8; ++e) {
                int k = ks * 32 + kg * 8 + e;
                float v = 0.0f;
                if (gr >= 0) {
                    if (k < XK) v = w_ih[gr * XK + k];
                    else if (k < XK + 50) v = w_hh[gr * 50 + (k - XK)];
                    else if (k == BIASK) v = b_ih[gr] + b_hh[gr];
                }
                unsigned short hb = f2bf(v);
                Wh[q][ks][e] = (short)hb;
                Wl[q][ks][e] = (short)f2bf(v - bf2f(hb));
            }
    }
}

// One layer-step: read ALL A-frags upfront (batched ds_reads, latency paid
// once), 2-term MFMA with chained acc, in-register cell update, bf16 h write.
template<int NT, int KS, int HK, bool WRB, bool LASTL>
__device__ __forceinline__ void step_body(
    int t, int T0, int lane,
    const short* Arh,            // act read buf
    short* Awh,                  // own act write buf (h at HK+n)
    short* Axh,                  // boundary buf (k=n), if WRB
    float* hfp,
    const short8 (&Wh)[NT][KS], const short8 (&Wl)[NT][KS],
    float (&cst)[NT])
{
    const int b = lane & 15, kg = lane >> 4;

    short8 Ah[KS];
    #pragma unroll
    for (int ks = 0; ks < KS; ++ks)
        Ah[ks] = *(const short8*)&Arh[(ks * 4 + kg) * 128 + b * 8];

    f32x4 acc[NT];
    #pragma unroll
    for (int q = 0; q < NT; ++q) acc[q] = (f32x4){0.0f, 0.0f, 0.0f, 0.0f};

    #pragma unroll
    for (int ks = 0; ks < KS; ++ks)
        #pragma unroll
        for (int q = 0; q < NT; ++q)
            acc[q] = __builtin_amdgcn_mfma_f32_16x16x32_bf16(Wh[q][ks], Ah[ks], acc[q], 0, 0, 0);
    #pragma unroll
    for (int ks = 0; ks < KS; ++ks)
        #pragma unroll
        for (int q = 0; q < NT; ++q)
            acc[q] = __builtin_amdgcn_mfma_f32_16x16x32_bf16(Wl[q][ks], Ah[ks], acc[q], 0, 0, 0);

    #pragma unroll
    for (int q = 0; q < NT; ++q) {
        int n = (T0 + q) * 4 + kg;
        if (n < 50) {
            float h = cell_upd(acc[q], cst[q]);
            unsigned short hb = f2bf(h);
            int k  = HK + n;
            Awh[(k >> 3) * 128 + b * 8 + (k & 7)] = (short)hb;
            if (WRB)
                Axh[(n >> 3) * 128 + b * 8 + (n & 7)] = (short)hb;
            if (LASTL && t == T_STEPS - 1) hfp[b * 56 + n] = h;
        }
    }
}

template<int NT, bool XST>
__device__ void role_l0(int T0, int lane, int b0, const float* __restrict__ xf,
    const float* w_ih, const float* w_hh, const float* b_ih, const float* b_hh,
    short (*A0h)[1024], short (*A1h)[2048])
{
    short8 Wh[NT][2], Wl[NT][2];
    load_wb<NT, 2, 8, 58>(T0, lane, w_ih, w_hh, b_ih, b_hh, Wh, Wl);
    float cst[NT];
    #pragma unroll
    for (int q = 0; q < NT; ++q) cst[q] = 0.0f;
    const int bb = lane & 15, kg = lane >> 4;

    for (int it = 0; it < T_STEPS + 2; ++it) {
        const bool stg = XST && (kg == 0) && (it + 1 < T_STEPS);
        float xs[8];
        if (stg) {
            const float* xr = &xf[((size_t)(b0 + bb) * T_STEPS + (it + 1)) * 8];
            *(float4*)&xs[0] = *(const float4*)xr;
            *(float4*)&xs[4] = *(const float4*)(xr + 4);
        }
        if (it < T_STEPS) {
            int cur = it & 1, nxt = cur ^ 1;
            step_body<NT, 2, 8, true, false>(it, T0, lane,
                A0h[cur], A0h[nxt], A1h[cur], nullptr, Wh, Wl, cst);
        }
        if (stg) {
            int nb = (it + 1) & 1;
            short8 hi;
            #pragma unroll
            for (int e = 0; e < 8; ++e) hi[e] = (short)f2bf(xs[e]);
            *(short8*)&A0h[nb][bb * 8] = hi;
        }
        BAR();
    }
}

// Mid-layer wave, NT=3. LASTL: L2 (skew 2, hf at t=255); else L1 (-> A2).
template<bool LASTL>
__device__ void role_mid(int T0, int lane,
    const float* w_ih, const float* w_hh, const float* b_ih, const float* b_hh,
    short (*Arh)[2048], short (*Axh)[2048], float* hfp)
{
    constexpr int SKEW = LASTL ? 2 : 1;
    short8 Wh[3][4], Wl[3][4];
    load_wb<3, 4, 50, 100>(T0, lane, w_ih, w_hh, b_ih, b_hh, Wh, Wl);
    float cst[3] = {0.0f, 0.0f, 0.0f};

    for (int it = 0; it < T_STEPS + 2; ++it) {
        int t = it - SKEW;
        if (t >= 0 && t < T_STEPS) {
            step_body<3, 4, 50, !LASTL, LASTL>(t, T0, lane,
                Arh[t & 1], Arh[(t + 1) & 1],
                LASTL ? (short*)nullptr : Axh[t & 1],
                hfp, Wh, Wl, cst);
        }
        BAR();
    }
}

// Fused dual-orphan: L1 tile12 (t1=it-1) + L2 tile12 (t2=it-2).
// All frags read upfront; the two 8-deep MFMA chains interleave.
__device__ void role_orphan(int lane,
    const float* w_ih1, const float* w_hh1, const float* b_ih1, const float* b_hh1,
    const float* w_ih2, const float* w_hh2, const float* b_ih2, const float* b_hh2,
    short (*A1h)[2048], short (*A2h)[2048], float* hfp)
{
    short8 W1h[1][4], W1l[1][4], W2h[1][4], W2l[1][4];
    load_wb<1, 4, 50, 100>(12, lane, w_ih1, w_hh1, b_ih1, b_hh1, W1h, W1l);
    load_wb<1, 4, 50, 100>(12, lane, w_ih2, w_hh2, b_ih2, b_hh2, W2h, W2l);
    float c1 = 0.0f, c2 = 0.0f;
    const int b = lane & 15, kg = lane >> 4;

    for (int it = 0; it < T_STEPS + 2; ++it) {
        int t1 = it - 1, t2 = it - 2;
        bool d1 = (unsigned)t1 < T_STEPS, d2 = (unsigned)t2 < T_STEPS;

        short8 A1[4], A2[4];
        #pragma unroll
        for (int ks = 0; ks < 4; ++ks) {
            int ga = (ks * 4 + kg) * 128 + b * 8;
            if (d1) A1[ks] = *(const short8*)&A1h[t1 & 1][ga];
            if (d2) A2[ks] = *(const short8*)&A2h[t2 & 1][ga];
        }

        f32x4 a1 = (f32x4){0.0f, 0.0f, 0.0f, 0.0f};
        f32x4 a2 = (f32x4){0.0f, 0.0f, 0.0f, 0.0f};
        #pragma unroll
        for (int ks = 0; ks < 4; ++ks) {
            if (d1) a1 = __builtin_amdgcn_mfma_f32_16x16x32_bf16(W1h[0][ks], A1[ks], a1, 0, 0, 0);
            if (d2) a2 = __builtin_amdgcn_mfma_f32_16x16x32_bf16(W2h[0][ks], A2[ks], a2, 0, 0, 0);
        }
        #pragma unroll
        for (int ks = 0; ks < 4; ++ks) {
            if (d1) a1 = __builtin_amdgcn_mfma_f32_16x16x32_bf16(W1l[0][ks], A1[ks], a1, 0, 0, 0);
            if (d2) a2 = __builtin_amdgcn_mfma_f32_16x16x32_bf16(W2l[0][ks], A2[ks], a2, 0, 0, 0);
        }

        const int n = 48 + kg;                     // valid kg<2
        if (d1 && kg < 2) {
            float h = cell_upd(a1, c1);
            unsigned short hb = f2bf(h);
            int k = 50 + n;
            A1h[(t1 + 1) & 1][(k >> 3) * 128 + b * 8 + (k & 7)] = (short)hb;
            A2h[t1 & 1][(n >> 3) * 128 + b * 8 + (n & 7)] = (short)hb;
        }
        if (d2 && kg < 2) {
            float h = cell_upd(a2, c2);
            unsigned short hb = f2bf(h);
            int k = 50 + n;
            A2h[(t2 + 1) & 1][(k >> 3) * 128 + b * 8 + (k & 7)] = (short)hb;
            if (t2 == T_STEPS - 1) hfp[b * 56 + n] = h;
        }
        BAR();
    }
}

__global__ __launch_bounds__(NTHR) void lstm_fused(
    const float* __restrict__ xf,
    const float* w_ih0, const float* w_hh0, const float* b_ih0, const float* b_hh0,
    const float* w_ih1, const float* w_hh1, const float* b_ih1, const float* b_hh1,
    const float* w_ih2, const float* w_hh2, const float* b_ih2, const float* b_hh2,
    const float* __restrict__ w_fc, const float* __restrict__ b_fc,
    float* __restrict__ out)
{
    __shared__ __align__(16) short A0h[2][1024];   // L0 act (K=64), bf16 hi only
    __shared__ __align__(16) short A1h[2][2048];   // L1 act (K=128)
    __shared__ __align__(16) short A2h[2][2048];   // L2 act (K=128)
    __shared__ __align__(16) float hf[16 * 56];

    const int tid  = threadIdx.x;
    const int lane = tid & 63;
    const int wid  = tid >> 6;
    const int b0   = blockIdx.x * 16;

    for (int i = tid; i < 2048; i += NTHR) ((short*)A0h)[i] = 0;
    for (int i = tid; i < 4096; i += NTHR) { ((short*)A1h)[i] = 0; ((short*)A2h)[i] = 0; }
    __syncthreads();

    // bias act columns = 1.0 (both bufs); x(0) -> A0 buf0
    if (tid < 32) {
        int buf = tid >> 4, b = tid & 15;
        A0h[buf][(58 >> 3) * 128 + b * 8 + (58 & 7)] = (short)0x3F80;
        A1h[buf][(100 >> 3) * 128 + b * 8 + (100 & 7)] = (short)0x3F80;
        A2h[buf][(100 >> 3) * 128 + b * 8 + (100 & 7)] = (short)0x3F80;
    }
    if (tid < 16) {
        int b = tid;
        #pragma unroll
        for (int j = 0; j < 8; ++j) {
            float v = xf[((size_t)(b0 + b) * T_STEPS + 0) * 8 + j];
            A0h[0][b * 8 + j] = (short)f2bf(v);
        }
    }
    __syncthreads();

    if      (wid == 0)  role_l0<5, false>(0, lane, b0, xf, w_ih0, w_hh0, b_ih0, b_hh0, A0h, A1h);
    else if (wid == 1)  role_l0<4, false>(5, lane, b0, xf, w_ih0, w_hh0, b_ih0, b_hh0, A0h, A1h);
    else if (wid == 2)  role_l0<4, true >(9, lane, b0, xf, w_ih0, w_hh0, b_ih0, b_hh0, A0h, A1h);
    else if (wid == 3)  role_mid<false>(0, lane, w_ih1, w_hh1, b_ih1, b_hh1, A1h, A2h, nullptr);
    else if (wid == 4)  role_mid<false>(3, lane, w_ih1, w_hh1, b_ih1, b_hh1, A1h, A2h, nullptr);
    else if (wid == 5)  role_mid<false>(6, lane, w_ih1, w_hh1, b_ih1, b_hh1, A1h, A2h, nullptr);
    else if (wid == 6)  role_mid<false>(9, lane, w_ih1, w_hh1, b_ih1, b_hh1, A1h, A2h, nullptr);
    else if (wid == 7)  role_mid<true >(0, lane, w_ih2, w_hh2, b_ih2, b_hh2, A2h, nullptr, hf);
    else if (wid == 8)  role_mid<true >(3, lane, w_ih2, w_hh2, b_ih2, b_hh2, A2h, nullptr, hf);
    else if (wid == 9)  role_mid<true >(6, lane, w_ih2, w_hh2, b_ih2, b_hh2, A2h, nullptr, hf);
    else if (wid == 10) role_mid<true >(9, lane, w_ih2, w_hh2, b_ih2, b_hh2, A2h, nullptr, hf);
    else                role_orphan(lane,
                            w_ih1, w_hh1, b_ih1, b_hh1,
                            w_ih2, w_hh2, b_ih2, b_hh2,
                            A1h, A2h, hf);

    __syncthreads();

    if (tid < 96) {
        int b = tid / 6, o = tid - b * 6;
        float a = b_fc[o];
        #pragma unroll
        for (int n = 0; n < 50; ++n)
            a = fmaf(w_fc[o * 50 + n], hf[b * 56 + n], a);
        out[(size_t)(b0 + b) * 6 + o] = a;
    }
}

extern "C" void kernel_launch(void* const* d_in, const int* in_sizes, int n_in,
                              void* d_out, int out_size, void* d_ws, size_t ws_size,
                              hipStream_t stream) {
    (void)in_sizes; (void)n_in; (void)d_ws; (void)ws_size; (void)out_size;

    const float* x     = (const float*)d_in[0];
    const float* w_ih0 = (const float*)d_in[1];
    const float* w_hh0 = (const float*)d_in[2];
    const float* b_ih0 = (const float*)d_in[3];
    const float* b_hh0 = (const float*)d_in[4];
    const float* w_ih1 = (const float*)d_in[5];
    const float* w_hh1 = (const float*)d_in[6];
    const float* b_ih1 = (const float*)d_in[7];
    const float* b_hh1 = (const float*)d_in[8];
    const float* w_ih2 = (const float*)d_in[9];
    const float* w_hh2 = (const float*)d_in[10];
    const float* b_ih2 = (const float*)d_in[11];
    const float* b_hh2 = (const float*)d_in[12];
    const float* w_fc  = (const float*)d_in[13];
    const float* b_fc  = (const float*)d_in[14];
    float* out = (float*)d_out;

    lstm_fused<<<dim3(BTOT / 16), dim3(NTHR), 0, stream>>>(
        x, w_ih0, w_hh0, b_ih0, b_hh0, w_ih1, w_hh1, b_ih1, b_hh1,
        w_ih2, w_hh2, b_ih2, b_hh2, w_fc, b_fc, out);
}